// Round 3
// baseline (369.004 us; speedup 1.0000x reference)
//
#include <hip/hip_runtime.h>
#include <hip/hip_bf16.h>

// InfiniteNeuralNetwork: the scan state stays row-constant, so
//   p[j] = (1/D) * prod_{d,k} cos^2(inf_w[d,j,k])
// and each infinite layer is just tanh(x @ cls_w + cls_b + p).
// Network = 6 GEMMs [2048x2048x2048] with fused epilogues.
// R2: 128x128 tile (min L2/L3 re-read traffic: 256MB/GEMM) + BK=64 +
//     double-buffered 2-phase prefetch (stage t+1 before compute t).

#define DD 2048
#define DEPTH 9

#define BM 128
#define BN 128
#define BK 64

typedef __attribute__((ext_vector_type(8))) short short8;
typedef __attribute__((ext_vector_type(4))) float f32x4;

__device__ __forceinline__ unsigned short f2bf(float f) {
  unsigned u = __float_as_uint(f);
  u += 0x7FFFu + ((u >> 16) & 1u);   // round-to-nearest-even
  return (unsigned short)(u >> 16);
}

// ---------------- prep kernels ----------------

__global__ void cvt_bf16_kernel(const float* __restrict__ s,
                                unsigned short* __restrict__ d, int n4) {
  int i = blockIdx.x * 256 + threadIdx.x;
  if (i >= n4) return;
  float4 v = reinterpret_cast<const float4*>(s)[i];
  ushort4 o;
  o.x = f2bf(v.x); o.y = f2bf(v.y); o.z = f2bf(v.z); o.w = f2bf(v.w);
  reinterpret_cast<ushort4*>(d)[i] = o;
}

// dst[z][n*D + k] = bf16(src_z[k*D + n])  for 6 weights in one launch
__global__ void transpose6_kernel(const float* __restrict__ s0,
                                  const float* __restrict__ s1,
                                  const float* __restrict__ s2,
                                  const float* __restrict__ s3,
                                  const float* __restrict__ s4,
                                  const float* __restrict__ s5,
                                  unsigned short* __restrict__ wts) {
  __shared__ float tile[32][33];
  const float* src;
  switch (blockIdx.z) {
    case 0: src = s0; break;
    case 1: src = s1; break;
    case 2: src = s2; break;
    case 3: src = s3; break;
    case 4: src = s4; break;
    default: src = s5; break;
  }
  unsigned short* dst = wts + (size_t)blockIdx.z * DD * DD;
  int bx = blockIdx.x * 32;  // n base
  int by = blockIdx.y * 32;  // k base
  int tx = threadIdx.x, ty = threadIdx.y;
#pragma unroll
  for (int i = ty; i < 32; i += 8)
    tile[i][tx] = src[(size_t)(by + i) * DD + bx + tx];
  __syncthreads();
#pragma unroll
  for (int i = ty; i < 32; i += 8)
    dst[(size_t)(bx + i) * DD + by + tx] = f2bf(tile[tx][i]);
}

// padd[j] = cls_b[j] + (1/D) * prod_{d,k} cos^2(inf_w[d,j,k])  (both layers)
__global__ void padd_kernel(const float* __restrict__ infw1,
                            const float* __restrict__ infw2,
                            const float* __restrict__ clsb1,
                            const float* __restrict__ clsb2,
                            float* __restrict__ padd1,
                            float* __restrict__ padd2) {
  int j = blockIdx.x * 256 + threadIdx.x;
  if (j >= DD) return;
  const float* inf_w = blockIdx.y ? infw2 : infw1;
  const float* cls_b = blockIdx.y ? clsb2 : clsb1;
  float* padd = blockIdx.y ? padd2 : padd1;
  float prod = 1.0f;
#pragma unroll
  for (int d = 0; d < DEPTH; ++d) {
    const float* row = inf_w + ((size_t)d * DD + j) * DD;
    prod *= cosf(row[0]) * cosf(row[1]) * cosf(row[2]);
  }
  padd[j] = cls_b[j] + prod * prod * (1.0f / (float)DD);
}

// ---------------- GEMM ----------------

__device__ __forceinline__ void gload_lds16(const unsigned short* g,
                                            unsigned short* l) {
  __builtin_amdgcn_global_load_lds(
      (const __attribute__((address_space(1))) void*)g,
      (__attribute__((address_space(3))) void*)l, 16, 0, 0);
}

// EPI: 0 = relu -> bf16, 1 = tanh -> bf16, 2 = relu -> f32
// A: [M][K] bf16 row-major. Bt: [N][K] bf16 (transposed weight). bias: [N] f32.
template <int EPI>
__global__ __launch_bounds__(256) void gemm_kernel(
    const unsigned short* __restrict__ A, const unsigned short* __restrict__ Bt,
    const float* __restrict__ bias, unsigned short* __restrict__ Cb,
    float* __restrict__ Cf) {
  const int N = DD, K = DD;
  __shared__ unsigned short As[2][BM * BK];  // 2 x 16KB
  __shared__ unsigned short Bs[2][BN * BK];  // 2 x 16KB

  int tid = threadIdx.x;
  int wid = tid >> 6, lane = tid & 63;
  int wr = wid >> 1, wc = wid & 1;   // wave grid 2x2, each wave 64x64
  int lr = lane & 15;
  int lg = lane >> 4;

  // XCD-aware bijective swizzle over 256 blocks.
  int bid = blockIdx.x;
  int swz = (bid & 7) * 32 + (bid >> 3);
  int bcol = (swz & 15) * BN;
  int brow = (swz >> 4) * BM;

  const unsigned short* Abase = A + (size_t)brow * K;
  const unsigned short* Bbase = Bt + (size_t)bcol * K;

  // per-lane staging source coords: 128 rows x 64 el tile = 1024 x 16B chunks
  // chunk = r*256 + tid; row = chunk>>3; kof = (chunk&7)*8; dst linear.
  auto stage = [&](int buf, int kt) {
#pragma unroll
    for (int r = 0; r < 4; ++r) {
      int chunk = r * 256 + tid;
      int row = chunk >> 3;
      int kof = (chunk & 7) * 8;
      gload_lds16(Abase + (size_t)row * K + kt + kof,
                  &As[buf][(size_t)(r * 256 + wid * 64) * 8]);
    }
#pragma unroll
    for (int r = 0; r < 4; ++r) {
      int chunk = r * 256 + tid;
      int row = chunk >> 3;
      int kof = (chunk & 7) * 8;
      gload_lds16(Bbase + (size_t)row * K + kt + kof,
                  &Bs[buf][(size_t)(r * 256 + wid * 64) * 8]);
    }
  };

  f32x4 acc[4][4];
#pragma unroll
  for (int i = 0; i < 4; ++i)
#pragma unroll
    for (int j = 0; j < 4; ++j) acc[i][j] = f32x4{0.f, 0.f, 0.f, 0.f};

  auto compute = [&](int buf) {
#pragma unroll
    for (int ks = 0; ks < 2; ++ks) {
      short8 a[4], b[4];
#pragma unroll
      for (int mt = 0; mt < 4; ++mt)
        a[mt] = *reinterpret_cast<const short8*>(
            &As[buf][(wr * 64 + mt * 16 + lr) * BK + ks * 32 + lg * 8]);
#pragma unroll
      for (int nt = 0; nt < 4; ++nt)
        b[nt] = *reinterpret_cast<const short8*>(
            &Bs[buf][(wc * 64 + nt * 16 + lr) * BK + ks * 32 + lg * 8]);
#pragma unroll
      for (int mt = 0; mt < 4; ++mt)
#pragma unroll
        for (int nt = 0; nt < 4; ++nt)
          acc[mt][nt] = __builtin_amdgcn_mfma_f32_16x16x32_bf16(
              a[mt], b[nt], acc[mt][nt], 0, 0, 0);
    }
  };

  // 2-phase prefetch: stage(t+1) issued before compute(t); one drain per tile.
  stage(0, 0);
  __syncthreads();                 // vmcnt(0)+lgkmcnt(0)+barrier
  int cur = 0;
  for (int kt = BK; kt < K; kt += BK) {
    stage(cur ^ 1, kt);            // next tile's loads fly under compute
    compute(cur);
    __syncthreads();
    cur ^= 1;
  }
  compute(cur);

  // epilogue: C/D layout col=lane&15, row=(lane>>4)*4+reg  [m89-verified]
#pragma unroll
  for (int nt = 0; nt < 4; ++nt) {
    int col = bcol + wc * 64 + nt * 16 + lr;
    float bs = bias[col];
#pragma unroll
    for (int mt = 0; mt < 4; ++mt) {
#pragma unroll
      for (int i = 0; i < 4; ++i) {
        int row = brow + wr * 64 + mt * 16 + lg * 4 + i;
        float v = acc[mt][nt][i] + bs;
        if (EPI == 1) v = tanhf(v);
        else v = fmaxf(v, 0.0f);
        if (EPI == 2) Cf[(size_t)row * N + col] = v;
        else Cb[(size_t)row * N + col] = f2bf(v);
      }
    }
  }
}

// ---------------- launch ----------------

extern "C" void kernel_launch(void* const* d_in, const int* in_sizes, int n_in,
                              void* d_out, int out_size, void* d_ws,
                              size_t ws_size, hipStream_t stream) {
  const float* x     = (const float*)d_in[0];
  const float* w0    = (const float*)d_in[1];
  const float* b0    = (const float*)d_in[2];
  const float* w1    = (const float*)d_in[3];
  const float* b1    = (const float*)d_in[4];
  const float* infw1 = (const float*)d_in[5];
  const float* clsw1 = (const float*)d_in[6];
  const float* clsb1 = (const float*)d_in[7];
  const float* w2    = (const float*)d_in[8];
  const float* b2    = (const float*)d_in[9];
  const float* infw2 = (const float*)d_in[10];
  const float* clsw2 = (const float*)d_in[11];
  const float* clsb2 = (const float*)d_in[12];
  const float* w3    = (const float*)d_in[13];
  const float* b3    = (const float*)d_in[14];
  float* out = (float*)d_out;

  char* ws = (char*)d_ws;
  const size_t MB = 1ull << 20;
  const size_t DDe = (size_t)DD * DD;
  unsigned short* buf0 = (unsigned short*)ws;              // 8 MB (x_bf16 / act)
  unsigned short* buf1 = (unsigned short*)(ws + 8 * MB);   // 8 MB (act)
  unsigned short* wts  = (unsigned short*)(ws + 16 * MB);  // 6 x 8 MB
  float* padd1 = (float*)(ws + 64 * MB);
  float* padd2 = padd1 + DD;

  transpose6_kernel<<<dim3(DD / 32, DD / 32, 6), dim3(32, 8), 0, stream>>>(
      w0, w1, clsw1, w2, clsw2, w3, wts);
  cvt_bf16_kernel<<<(int)(DDe / 4 / 256), 256, 0, stream>>>(x, buf0,
                                                            (int)(DDe / 4));
  padd_kernel<<<dim3(DD / 256, 2), 256, 0, stream>>>(infw1, infw2, clsb1,
                                                     clsb2, padd1, padd2);

  dim3 gg((DD / BM) * (DD / BN));  // 256 blocks
  gemm_kernel<0><<<gg, 256, 0, stream>>>(buf0, wts + 0 * DDe, b0,    buf1, nullptr);
  gemm_kernel<0><<<gg, 256, 0, stream>>>(buf1, wts + 1 * DDe, b1,    buf0, nullptr);
  gemm_kernel<1><<<gg, 256, 0, stream>>>(buf0, wts + 2 * DDe, padd1, buf1, nullptr);
  gemm_kernel<0><<<gg, 256, 0, stream>>>(buf1, wts + 3 * DDe, b2,    buf0, nullptr);
  gemm_kernel<1><<<gg, 256, 0, stream>>>(buf0, wts + 4 * DDe, padd2, buf1, nullptr);
  gemm_kernel<2><<<gg, 256, 0, stream>>>(buf1, wts + 5 * DDe, b3,    nullptr, out);
}

// Round 4
// 287.140 us; speedup vs baseline: 1.2851x; 1.2851x over previous
//
#include <hip/hip_runtime.h>
#include <hip/hip_bf16.h>

// InfiniteNeuralNetwork: the scan state stays row-constant, so
//   p[j] = (1/D) * prod_{d,k} cos^2(inf_w[d,j,k])
// and each infinite layer is just tanh(x @ cls_w + cls_b + p).
// Network = 6 GEMMs [2048x2048x2048] with fused epilogues.
// R2: 128x128 tile + BK=64 + dbuf 2-phase prefetch  -> 16-way LDS read
//     conflicts (stride 128B), 6.29M conflict cycles, 93us/GEMM. BAD.
// R3: XOR-swizzle (T2, rule-21 both-sides): linear LDS dest, pre-swizzled
//     global source slot (slot ^= row&7, 16B granules), same XOR on ds_read.

#define DD 2048
#define DEPTH 9

#define BM 128
#define BN 128
#define BK 64

typedef __attribute__((ext_vector_type(8))) short short8;
typedef __attribute__((ext_vector_type(4))) float f32x4;

__device__ __forceinline__ unsigned short f2bf(float f) {
  unsigned u = __float_as_uint(f);
  u += 0x7FFFu + ((u >> 16) & 1u);   // round-to-nearest-even
  return (unsigned short)(u >> 16);
}

// ---------------- prep kernels ----------------

__global__ void cvt_bf16_kernel(const float* __restrict__ s,
                                unsigned short* __restrict__ d, int n4) {
  int i = blockIdx.x * 256 + threadIdx.x;
  if (i >= n4) return;
  float4 v = reinterpret_cast<const float4*>(s)[i];
  ushort4 o;
  o.x = f2bf(v.x); o.y = f2bf(v.y); o.z = f2bf(v.z); o.w = f2bf(v.w);
  reinterpret_cast<ushort4*>(d)[i] = o;
}

// dst[z][n*D + k] = bf16(src_z[k*D + n])  for 6 weights in one launch
__global__ void transpose6_kernel(const float* __restrict__ s0,
                                  const float* __restrict__ s1,
                                  const float* __restrict__ s2,
                                  const float* __restrict__ s3,
                                  const float* __restrict__ s4,
                                  const float* __restrict__ s5,
                                  unsigned short* __restrict__ wts) {
  __shared__ float tile[32][33];
  const float* src;
  switch (blockIdx.z) {
    case 0: src = s0; break;
    case 1: src = s1; break;
    case 2: src = s2; break;
    case 3: src = s3; break;
    case 4: src = s4; break;
    default: src = s5; break;
  }
  unsigned short* dst = wts + (size_t)blockIdx.z * DD * DD;
  int bx = blockIdx.x * 32;  // n base
  int by = blockIdx.y * 32;  // k base
  int tx = threadIdx.x, ty = threadIdx.y;
#pragma unroll
  for (int i = ty; i < 32; i += 8)
    tile[i][tx] = src[(size_t)(by + i) * DD + bx + tx];
  __syncthreads();
#pragma unroll
  for (int i = ty; i < 32; i += 8)
    dst[(size_t)(bx + i) * DD + by + tx] = f2bf(tile[tx][i]);
}

// padd[j] = cls_b[j] + (1/D) * prod_{d,k} cos^2(inf_w[d,j,k])  (both layers)
__global__ void padd_kernel(const float* __restrict__ infw1,
                            const float* __restrict__ infw2,
                            const float* __restrict__ clsb1,
                            const float* __restrict__ clsb2,
                            float* __restrict__ padd1,
                            float* __restrict__ padd2) {
  int j = blockIdx.x * 256 + threadIdx.x;
  if (j >= DD) return;
  const float* inf_w = blockIdx.y ? infw2 : infw1;
  const float* cls_b = blockIdx.y ? clsb2 : clsb1;
  float* padd = blockIdx.y ? padd2 : padd1;
  float prod = 1.0f;
#pragma unroll
  for (int d = 0; d < DEPTH; ++d) {
    const float* row = inf_w + ((size_t)d * DD + j) * DD;
    prod *= cosf(row[0]) * cosf(row[1]) * cosf(row[2]);
  }
  padd[j] = cls_b[j] + prod * prod * (1.0f / (float)DD);
}

// ---------------- GEMM ----------------

__device__ __forceinline__ void gload_lds16(const unsigned short* g,
                                            unsigned short* l) {
  __builtin_amdgcn_global_load_lds(
      (const __attribute__((address_space(1))) void*)g,
      (__attribute__((address_space(3))) void*)l, 16, 0, 0);
}

// EPI: 0 = relu -> bf16, 1 = tanh -> bf16, 2 = relu -> f32
// A: [M][K] bf16 row-major. Bt: [N][K] bf16 (transposed weight). bias: [N] f32.
template <int EPI>
__global__ __launch_bounds__(256) void gemm_kernel(
    const unsigned short* __restrict__ A, const unsigned short* __restrict__ Bt,
    const float* __restrict__ bias, unsigned short* __restrict__ Cb,
    float* __restrict__ Cf) {
  const int N = DD, K = DD;
  __shared__ unsigned short As[2][BM * BK];  // 2 x 16KB
  __shared__ unsigned short Bs[2][BN * BK];  // 2 x 16KB

  int tid = threadIdx.x;
  int wid = tid >> 6, lane = tid & 63;
  int wr = wid >> 1, wc = wid & 1;   // wave grid 2x2, each wave 64x64
  int lr = lane & 15;
  int lg = lane >> 4;

  // XCD-aware bijective swizzle over 256 blocks.
  int bid = blockIdx.x;
  int swz = (bid & 7) * 32 + (bid >> 3);
  int bcol = (swz & 15) * BN;
  int brow = (swz >> 4) * BM;

  const unsigned short* Abase = A + (size_t)brow * K;
  const unsigned short* Bbase = Bt + (size_t)bcol * K;

  // Staging with pre-swizzled SOURCE (rule 21): LDS dest stays linear so
  // physical chunk (row, sp) holds logical slot sp^(row&7). 16B granules.
  auto stage = [&](int buf, int kt) {
#pragma unroll
    for (int r = 0; r < 4; ++r) {
      int chunk = r * 256 + tid;          // 0..1023
      int row = chunk >> 3;               // 8 x 16B chunks per 128B row
      int sp = chunk & 7;
      int kof = (sp ^ (row & 7)) * 8;     // pre-swizzled source slot
      gload_lds16(Abase + (size_t)row * K + kt + kof,
                  &As[buf][(size_t)(r * 256 + wid * 64) * 8]);
    }
#pragma unroll
    for (int r = 0; r < 4; ++r) {
      int chunk = r * 256 + tid;
      int row = chunk >> 3;
      int sp = chunk & 7;
      int kof = (sp ^ (row & 7)) * 8;
      gload_lds16(Bbase + (size_t)row * K + kt + kof,
                  &Bs[buf][(size_t)(r * 256 + wid * 64) * 8]);
    }
  };

  f32x4 acc[4][4];
#pragma unroll
  for (int i = 0; i < 4; ++i)
#pragma unroll
    for (int j = 0; j < 4; ++j) acc[i][j] = f32x4{0.f, 0.f, 0.f, 0.f};

  auto compute = [&](int buf) {
#pragma unroll
    for (int ks = 0; ks < 2; ++ks) {
      short8 a[4], b[4];
#pragma unroll
      for (int mt = 0; mt < 4; ++mt) {
        int row = wr * 64 + mt * 16 + lr;
        int slot = (ks * 4 + lg) ^ (row & 7);   // same involution as stage
        a[mt] = *reinterpret_cast<const short8*>(
            &As[buf][row * BK + slot * 8]);
      }
#pragma unroll
      for (int nt = 0; nt < 4; ++nt) {
        int row = wc * 64 + nt * 16 + lr;
        int slot = (ks * 4 + lg) ^ (row & 7);
        b[nt] = *reinterpret_cast<const short8*>(
            &Bs[buf][row * BK + slot * 8]);
      }
#pragma unroll
      for (int mt = 0; mt < 4; ++mt)
#pragma unroll
        for (int nt = 0; nt < 4; ++nt)
          acc[mt][nt] = __builtin_amdgcn_mfma_f32_16x16x32_bf16(
              a[mt], b[nt], acc[mt][nt], 0, 0, 0);
    }
  };

  // 2-phase prefetch: stage(t+1) issued before compute(t); one drain per tile.
  stage(0, 0);
  __syncthreads();                 // vmcnt(0)+lgkmcnt(0)+barrier
  int cur = 0;
  for (int kt = BK; kt < K; kt += BK) {
    stage(cur ^ 1, kt);            // next tile's loads fly under compute
    compute(cur);
    __syncthreads();
    cur ^= 1;
  }
  compute(cur);

  // epilogue: C/D layout col=lane&15, row=(lane>>4)*4+reg  [m89-verified]
#pragma unroll
  for (int nt = 0; nt < 4; ++nt) {
    int col = bcol + wc * 64 + nt * 16 + lr;
    float bs = bias[col];
#pragma unroll
    for (int mt = 0; mt < 4; ++mt) {
#pragma unroll
      for (int i = 0; i < 4; ++i) {
        int row = brow + wr * 64 + mt * 16 + lg * 4 + i;
        float v = acc[mt][nt][i] + bs;
        if (EPI == 1) v = tanhf(v);
        else v = fmaxf(v, 0.0f);
        if (EPI == 2) Cf[(size_t)row * N + col] = v;
        else Cb[(size_t)row * N + col] = f2bf(v);
      }
    }
  }
}

// ---------------- launch ----------------

extern "C" void kernel_launch(void* const* d_in, const int* in_sizes, int n_in,
                              void* d_out, int out_size, void* d_ws,
                              size_t ws_size, hipStream_t stream) {
  const float* x     = (const float*)d_in[0];
  const float* w0    = (const float*)d_in[1];
  const float* b0    = (const float*)d_in[2];
  const float* w1    = (const float*)d_in[3];
  const float* b1    = (const float*)d_in[4];
  const float* infw1 = (const float*)d_in[5];
  const float* clsw1 = (const float*)d_in[6];
  const float* clsb1 = (const float*)d_in[7];
  const float* w2    = (const float*)d_in[8];
  const float* b2    = (const float*)d_in[9];
  const float* infw2 = (const float*)d_in[10];
  const float* clsw2 = (const float*)d_in[11];
  const float* clsb2 = (const float*)d_in[12];
  const float* w3    = (const float*)d_in[13];
  const float* b3    = (const float*)d_in[14];
  float* out = (float*)d_out;

  char* ws = (char*)d_ws;
  const size_t MB = 1ull << 20;
  const size_t DDe = (size_t)DD * DD;
  unsigned short* buf0 = (unsigned short*)ws;              // 8 MB (x_bf16 / act)
  unsigned short* buf1 = (unsigned short*)(ws + 8 * MB);   // 8 MB (act)
  unsigned short* wts  = (unsigned short*)(ws + 16 * MB);  // 6 x 8 MB
  float* padd1 = (float*)(ws + 64 * MB);
  float* padd2 = padd1 + DD;

  transpose6_kernel<<<dim3(DD / 32, DD / 32, 6), dim3(32, 8), 0, stream>>>(
      w0, w1, clsw1, w2, clsw2, w3, wts);
  cvt_bf16_kernel<<<(int)(DDe / 4 / 256), 256, 0, stream>>>(x, buf0,
                                                            (int)(DDe / 4));
  padd_kernel<<<dim3(DD / 256, 2), 256, 0, stream>>>(infw1, infw2, clsb1,
                                                     clsb2, padd1, padd2);

  dim3 gg((DD / BM) * (DD / BN));  // 256 blocks
  gemm_kernel<0><<<gg, 256, 0, stream>>>(buf0, wts + 0 * DDe, b0,    buf1, nullptr);
  gemm_kernel<0><<<gg, 256, 0, stream>>>(buf1, wts + 1 * DDe, b1,    buf0, nullptr);
  gemm_kernel<1><<<gg, 256, 0, stream>>>(buf0, wts + 2 * DDe, padd1, buf1, nullptr);
  gemm_kernel<0><<<gg, 256, 0, stream>>>(buf1, wts + 3 * DDe, b2,    buf0, nullptr);
  gemm_kernel<1><<<gg, 256, 0, stream>>>(buf0, wts + 4 * DDe, padd2, buf1, nullptr);
  gemm_kernel<2><<<gg, 256, 0, stream>>>(buf1, wts + 5 * DDe, b3,    nullptr, out);
}

// Round 5
// 259.712 us; speedup vs baseline: 1.4208x; 1.1056x over previous
//
#include <hip/hip_runtime.h>
#include <hip/hip_bf16.h>

// InfiniteNeuralNetwork: the scan state stays row-constant, so
//   p[j] = (1/D) * prod_{d,k} cos^2(inf_w[d,j,k])
// and each infinite layer is just tanh(x @ cls_w + cls_b + p).
// Network = 6 GEMMs [2048x2048x2048] with fused epilogues.
// R3: XOR-swizzle fixed 16-way LDS conflicts (93 -> ~41us/GEMM).
// R4: depth-3 pipeline, counted vmcnt(16) (T3+T4): raw s_barrier, never
//     drain vmcnt to 0 in the main loop. 2 K-steps of latency cover.

#define DD 2048
#define DEPTH 9

#define BM 128
#define BN 128
#define BK 64
#define NT (DD / BK)   // 32 K-tiles

typedef __attribute__((ext_vector_type(8))) short short8;
typedef __attribute__((ext_vector_type(4))) float f32x4;

__device__ __forceinline__ unsigned short f2bf(float f) {
  unsigned u = __float_as_uint(f);
  u += 0x7FFFu + ((u >> 16) & 1u);   // round-to-nearest-even
  return (unsigned short)(u >> 16);
}

// ---------------- prep kernels ----------------

__global__ void cvt_bf16_kernel(const float* __restrict__ s,
                                unsigned short* __restrict__ d, int n4) {
  int i = blockIdx.x * 256 + threadIdx.x;
  if (i >= n4) return;
  float4 v = reinterpret_cast<const float4*>(s)[i];
  ushort4 o;
  o.x = f2bf(v.x); o.y = f2bf(v.y); o.z = f2bf(v.z); o.w = f2bf(v.w);
  reinterpret_cast<ushort4*>(d)[i] = o;
}

// dst[z][n*D + k] = bf16(src_z[k*D + n])  for 6 weights in one launch
__global__ void transpose6_kernel(const float* __restrict__ s0,
                                  const float* __restrict__ s1,
                                  const float* __restrict__ s2,
                                  const float* __restrict__ s3,
                                  const float* __restrict__ s4,
                                  const float* __restrict__ s5,
                                  unsigned short* __restrict__ wts) {
  __shared__ float tile[32][33];
  const float* src;
  switch (blockIdx.z) {
    case 0: src = s0; break;
    case 1: src = s1; break;
    case 2: src = s2; break;
    case 3: src = s3; break;
    case 4: src = s4; break;
    default: src = s5; break;
  }
  unsigned short* dst = wts + (size_t)blockIdx.z * DD * DD;
  int bx = blockIdx.x * 32;  // n base
  int by = blockIdx.y * 32;  // k base
  int tx = threadIdx.x, ty = threadIdx.y;
#pragma unroll
  for (int i = ty; i < 32; i += 8)
    tile[i][tx] = src[(size_t)(by + i) * DD + bx + tx];
  __syncthreads();
#pragma unroll
  for (int i = ty; i < 32; i += 8)
    dst[(size_t)(bx + i) * DD + by + tx] = f2bf(tile[tx][i]);
}

// padd[j] = cls_b[j] + (1/D) * prod_{d,k} cos^2(inf_w[d,j,k])  (both layers)
__global__ void padd_kernel(const float* __restrict__ infw1,
                            const float* __restrict__ infw2,
                            const float* __restrict__ clsb1,
                            const float* __restrict__ clsb2,
                            float* __restrict__ padd1,
                            float* __restrict__ padd2) {
  int j = blockIdx.x * 256 + threadIdx.x;
  if (j >= DD) return;
  const float* inf_w = blockIdx.y ? infw2 : infw1;
  const float* cls_b = blockIdx.y ? clsb2 : clsb1;
  float* padd = blockIdx.y ? padd2 : padd1;
  float prod = 1.0f;
#pragma unroll
  for (int d = 0; d < DEPTH; ++d) {
    const float* row = inf_w + ((size_t)d * DD + j) * DD;
    prod *= cosf(row[0]) * cosf(row[1]) * cosf(row[2]);
  }
  padd[j] = cls_b[j] + prod * prod * (1.0f / (float)DD);
}

// ---------------- GEMM ----------------

__device__ __forceinline__ void gload_lds16(const unsigned short* g,
                                            unsigned short* l) {
  __builtin_amdgcn_global_load_lds(
      (const __attribute__((address_space(1))) void*)g,
      (__attribute__((address_space(3))) void*)l, 16, 0, 0);
}

__device__ __forceinline__ void waitv16() {
  asm volatile("s_waitcnt vmcnt(16)" ::: "memory");
}
__device__ __forceinline__ void waitv8() {
  asm volatile("s_waitcnt vmcnt(8)" ::: "memory");
}
__device__ __forceinline__ void waitv0() {
  asm volatile("s_waitcnt vmcnt(0)" ::: "memory");
}
__device__ __forceinline__ void waitlgkm0() {
  asm volatile("s_waitcnt lgkmcnt(0)" ::: "memory");
}

// EPI: 0 = relu -> bf16, 1 = tanh -> bf16, 2 = relu -> f32
// A: [M][K] bf16 row-major. Bt: [N][K] bf16 (transposed weight). bias: [N] f32.
template <int EPI>
__global__ __launch_bounds__(256) void gemm_kernel(
    const unsigned short* __restrict__ A, const unsigned short* __restrict__ Bt,
    const float* __restrict__ bias, unsigned short* __restrict__ Cb,
    float* __restrict__ Cf) {
  const int N = DD, K = DD;
  __shared__ unsigned short As[3][BM * BK];  // 3 x 16KB
  __shared__ unsigned short Bs[3][BN * BK];  // 3 x 16KB

  int tid = threadIdx.x;
  int wid = tid >> 6, lane = tid & 63;
  int wr = wid >> 1, wc = wid & 1;   // wave grid 2x2, each wave 64x64
  int lr = lane & 15;
  int lg = lane >> 4;

  // XCD-aware bijective swizzle over 256 blocks.
  int bid = blockIdx.x;
  int swz = (bid & 7) * 32 + (bid >> 3);
  int bcol = (swz & 15) * BN;
  int brow = (swz >> 4) * BM;

  const unsigned short* Abase = A + (size_t)brow * K;
  const unsigned short* Bbase = Bt + (size_t)bcol * K;

  // Staging with pre-swizzled SOURCE (rule 21): LDS dest stays linear so
  // physical chunk (row, sp) holds logical slot sp^(row&7). 16B granules.
  // 8 global_load_lds per thread per tile (4 A + 4 B) -> vmcnt units.
  auto stage = [&](int buf, int tile) {
    int kt = tile * BK;
#pragma unroll
    for (int r = 0; r < 4; ++r) {
      int chunk = r * 256 + tid;          // 0..1023
      int row = chunk >> 3;               // 8 x 16B chunks per 128B row
      int sp = chunk & 7;
      int kof = (sp ^ (row & 7)) * 8;     // pre-swizzled source slot
      gload_lds16(Abase + (size_t)row * K + kt + kof,
                  &As[buf][(size_t)(r * 256 + wid * 64) * 8]);
    }
#pragma unroll
    for (int r = 0; r < 4; ++r) {
      int chunk = r * 256 + tid;
      int row = chunk >> 3;
      int sp = chunk & 7;
      int kof = (sp ^ (row & 7)) * 8;
      gload_lds16(Bbase + (size_t)row * K + kt + kof,
                  &Bs[buf][(size_t)(r * 256 + wid * 64) * 8]);
    }
  };

  f32x4 acc[4][4];
#pragma unroll
  for (int i = 0; i < 4; ++i)
#pragma unroll
    for (int j = 0; j < 4; ++j) acc[i][j] = f32x4{0.f, 0.f, 0.f, 0.f};

  auto compute = [&](int buf) {
#pragma unroll
    for (int ks = 0; ks < 2; ++ks) {
      short8 a[4], b[4];
#pragma unroll
      for (int mt = 0; mt < 4; ++mt) {
        int row = wr * 64 + mt * 16 + lr;
        int slot = (ks * 4 + lg) ^ (row & 7);   // same involution as stage
        a[mt] = *reinterpret_cast<const short8*>(
            &As[buf][row * BK + slot * 8]);
      }
#pragma unroll
      for (int nt = 0; nt < 4; ++nt) {
        int row = wc * 64 + nt * 16 + lr;
        int slot = (ks * 4 + lg) ^ (row & 7);
        b[nt] = *reinterpret_cast<const short8*>(
            &Bs[buf][row * BK + slot * 8]);
      }
#pragma unroll
      for (int mt = 0; mt < 4; ++mt)
#pragma unroll
        for (int nt = 0; nt < 4; ++nt)
          acc[mt][nt] = __builtin_amdgcn_mfma_f32_16x16x32_bf16(
              a[mt], b[nt], acc[mt][nt], 0, 0, 0);
    }
  };

  // One pipeline step: consume tile `t` from buffer `buf`, prefetch t+3.
  // wcase: 0 -> vmcnt(16) (3 tiles in flight), 1 -> vmcnt(8), 2 -> vmcnt(0).
  auto step = [&](int buf, int pf_tile, int wcase) {
    if (wcase == 0) waitv16();
    else if (wcase == 1) waitv8();
    else waitv0();
    __builtin_amdgcn_s_barrier();          // buffer `buf` fully written
    __builtin_amdgcn_sched_barrier(0);
    compute(buf);
    waitlgkm0();                           // my ds_reads retired
    __builtin_amdgcn_s_barrier();          // all waves done reading `buf`
    __builtin_amdgcn_sched_barrier(0);
    if (pf_tile < NT) stage(buf, pf_tile);
  };

  // prologue: 3 tiles in flight (24 vmem/thread outstanding)
  stage(0, 0); stage(1, 1); stage(2, 2);
#pragma unroll 1
  for (int i = 0; i < 10; ++i) {           // tiles 0..29
    int t = 3 * i;
    step(0, t + 3, 0);
    step(1, t + 4, 0);
    step(2, t + 5, 0);
  }
  step(0, NT, 1);                          // tile 30: 2 tiles in flight
  step(1, NT, 2);                          // tile 31: last

  // epilogue: C/D layout col=lane&15, row=(lane>>4)*4+reg  [m89-verified]
#pragma unroll
  for (int nt = 0; nt < 4; ++nt) {
    int col = bcol + wc * 64 + nt * 16 + lr;
    float bs = bias[col];
#pragma unroll
    for (int mt = 0; mt < 4; ++mt) {
#pragma unroll
      for (int i = 0; i < 4; ++i) {
        int row = brow + wr * 64 + mt * 16 + lg * 4 + i;
        float v = acc[mt][nt][i] + bs;
        if (EPI == 1) v = tanhf(v);
        else v = fmaxf(v, 0.0f);
        if (EPI == 2) Cf[(size_t)row * N + col] = v;
        else Cb[(size_t)row * N + col] = f2bf(v);
      }
    }
  }
}

// ---------------- launch ----------------

extern "C" void kernel_launch(void* const* d_in, const int* in_sizes, int n_in,
                              void* d_out, int out_size, void* d_ws,
                              size_t ws_size, hipStream_t stream) {
  const float* x     = (const float*)d_in[0];
  const float* w0    = (const float*)d_in[1];
  const float* b0    = (const float*)d_in[2];
  const float* w1    = (const float*)d_in[3];
  const float* b1    = (const float*)d_in[4];
  const float* infw1 = (const float*)d_in[5];
  const float* clsw1 = (const float*)d_in[6];
  const float* clsb1 = (const float*)d_in[7];
  const float* w2    = (const float*)d_in[8];
  const float* b2    = (const float*)d_in[9];
  const float* infw2 = (const float*)d_in[10];
  const float* clsw2 = (const float*)d_in[11];
  const float* clsb2 = (const float*)d_in[12];
  const float* w3    = (const float*)d_in[13];
  const float* b3    = (const float*)d_in[14];
  float* out = (float*)d_out;

  char* ws = (char*)d_ws;
  const size_t MB = 1ull << 20;
  const size_t DDe = (size_t)DD * DD;
  unsigned short* buf0 = (unsigned short*)ws;              // 8 MB (x_bf16 / act)
  unsigned short* buf1 = (unsigned short*)(ws + 8 * MB);   // 8 MB (act)
  unsigned short* wts  = (unsigned short*)(ws + 16 * MB);  // 6 x 8 MB
  float* padd1 = (float*)(ws + 64 * MB);
  float* padd2 = padd1 + DD;

  transpose6_kernel<<<dim3(DD / 32, DD / 32, 6), dim3(32, 8), 0, stream>>>(
      w0, w1, clsw1, w2, clsw2, w3, wts);
  cvt_bf16_kernel<<<(int)(DDe / 4 / 256), 256, 0, stream>>>(x, buf0,
                                                            (int)(DDe / 4));
  padd_kernel<<<dim3(DD / 256, 2), 256, 0, stream>>>(infw1, infw2, clsb1,
                                                     clsb2, padd1, padd2);

  dim3 gg((DD / BM) * (DD / BN));  // 256 blocks
  gemm_kernel<0><<<gg, 256, 0, stream>>>(buf0, wts + 0 * DDe, b0,    buf1, nullptr);
  gemm_kernel<0><<<gg, 256, 0, stream>>>(buf1, wts + 1 * DDe, b1,    buf0, nullptr);
  gemm_kernel<1><<<gg, 256, 0, stream>>>(buf0, wts + 2 * DDe, padd1, buf1, nullptr);
  gemm_kernel<0><<<gg, 256, 0, stream>>>(buf1, wts + 3 * DDe, b2,    buf0, nullptr);
  gemm_kernel<1><<<gg, 256, 0, stream>>>(buf0, wts + 4 * DDe, padd2, buf1, nullptr);
  gemm_kernel<2><<<gg, 256, 0, stream>>>(buf1, wts + 5 * DDe, b3,    nullptr, out);
}

// Round 6
// 247.512 us; speedup vs baseline: 1.4908x; 1.0493x over previous
//
#include <hip/hip_runtime.h>
#include <hip/hip_bf16.h>

// InfiniteNeuralNetwork: the scan state stays row-constant, so
//   p[j] = (1/D) * prod_{d,k} cos^2(inf_w[d,j,k])
// and each infinite layer is just tanh(x @ cls_w + cls_b + p).
// Network = 6 GEMMs [2048x2048x2048] with fused epilogues.
// R3: XOR-swizzle fixed 16-way LDS conflicts (93 -> ~41us/GEMM).
// R4: depth-3 counted-vmcnt pipeline (~35us/GEMM). Still 1 block/CU.
// R5: BN=64/BK=32 -> 512 blocks = 2 blocks/CU (cross-block overlap) with
//     swizzle + depth-3 pipeline; transposes of later weights hidden in
//     GEMM tails (GEMM_i transposes weight for GEMM_{i+2}).

#define DD 2048
#define DEPTH 9

#define BM 128
#define BN 64
#define BK 32
#define NT (DD / BK)   // 64 K-tiles

typedef __attribute__((ext_vector_type(8))) short short8;
typedef __attribute__((ext_vector_type(4))) float f32x4;

__device__ __forceinline__ unsigned short f2bf(float f) {
  unsigned u = __float_as_uint(f);
  u += 0x7FFFu + ((u >> 16) & 1u);   // round-to-nearest-even
  return (unsigned short)(u >> 16);
}

// ---------------- prep kernels ----------------

__global__ void cvt_bf16_kernel(const float* __restrict__ s,
                                unsigned short* __restrict__ d, int n4) {
  int i = blockIdx.x * 256 + threadIdx.x;
  if (i >= n4) return;
  float4 v = reinterpret_cast<const float4*>(s)[i];
  ushort4 o;
  o.x = f2bf(v.x); o.y = f2bf(v.y); o.z = f2bf(v.z); o.w = f2bf(v.w);
  reinterpret_cast<ushort4*>(d)[i] = o;
}

// dst[z][n*D + k] = bf16(src_z[k*D + n])  for w0, w1 (needed immediately)
__global__ void transpose2_kernel(const float* __restrict__ s0,
                                  const float* __restrict__ s1,
                                  unsigned short* __restrict__ wts) {
  __shared__ float tile[32][33];
  const float* src = blockIdx.z ? s1 : s0;
  unsigned short* dst = wts + (size_t)blockIdx.z * DD * DD;
  int bx = blockIdx.x * 32;  // n base
  int by = blockIdx.y * 32;  // k base
  int tx = threadIdx.x, ty = threadIdx.y;
#pragma unroll
  for (int i = ty; i < 32; i += 8)
    tile[i][tx] = src[(size_t)(by + i) * DD + bx + tx];
  __syncthreads();
#pragma unroll
  for (int i = ty; i < 32; i += 8)
    dst[(size_t)(bx + i) * DD + by + tx] = f2bf(tile[tx][i]);
}

// padd[j] = cls_b[j] + (1/D) * prod_{d,k} cos^2(inf_w[d,j,k])  (both layers)
__global__ void padd_kernel(const float* __restrict__ infw1,
                            const float* __restrict__ infw2,
                            const float* __restrict__ clsb1,
                            const float* __restrict__ clsb2,
                            float* __restrict__ padd1,
                            float* __restrict__ padd2) {
  int j = blockIdx.x * 256 + threadIdx.x;
  if (j >= DD) return;
  const float* inf_w = blockIdx.y ? infw2 : infw1;
  const float* cls_b = blockIdx.y ? clsb2 : clsb1;
  float* padd = blockIdx.y ? padd2 : padd1;
  float prod = 1.0f;
#pragma unroll
  for (int d = 0; d < DEPTH; ++d) {
    const float* row = inf_w + ((size_t)d * DD + j) * DD;
    prod *= cosf(row[0]) * cosf(row[1]) * cosf(row[2]);
  }
  padd[j] = cls_b[j] + prod * prod * (1.0f / (float)DD);
}

// ---------------- GEMM ----------------

__device__ __forceinline__ void gload_lds16(const unsigned short* g,
                                            unsigned short* l) {
  __builtin_amdgcn_global_load_lds(
      (const __attribute__((address_space(1))) void*)g,
      (__attribute__((address_space(3))) void*)l, 16, 0, 0);
}

__device__ __forceinline__ void waitv6() {
  asm volatile("s_waitcnt vmcnt(6)" ::: "memory");
}
__device__ __forceinline__ void waitv3() {
  asm volatile("s_waitcnt vmcnt(3)" ::: "memory");
}
__device__ __forceinline__ void waitv0() {
  asm volatile("s_waitcnt vmcnt(0)" ::: "memory");
}
__device__ __forceinline__ void waitlgkm0() {
  asm volatile("s_waitcnt lgkmcnt(0)" ::: "memory");
}

// EPI: 0 = relu -> bf16, 1 = tanh -> bf16, 2 = relu -> f32
// A: [M][K] bf16 row-major. Bt: [N][K] bf16 (transposed weight). bias: [N] f32.
// tsrc/tdst: optional weight transpose tail (for a LATER gemm's weight).
template <int EPI>
__global__ __launch_bounds__(256) void gemm_kernel(
    const unsigned short* __restrict__ A, const unsigned short* __restrict__ Bt,
    const float* __restrict__ bias, unsigned short* __restrict__ Cb,
    float* __restrict__ Cf, const float* __restrict__ tsrc,
    unsigned short* __restrict__ tdst) {
  const int N = DD, K = DD;
  __shared__ unsigned short As[3][BM * BK];  // 3 x 8KB
  __shared__ unsigned short Bs[3][BN * BK];  // 3 x 4KB

  int tid = threadIdx.x;
  int wid = tid >> 6, lane = tid & 63;
  int wr = wid >> 1, wc = wid & 1;   // wave grid 2x2, wave tile 64x32
  int lr = lane & 15;
  int lg = lane >> 4;

  // XCD-aware bijective swizzle over 512 blocks (512 % 8 == 0).
  int bid = blockIdx.x;
  int swz = (bid & 7) * 64 + (bid >> 3);
  int bcol = (swz & 31) * BN;   // 32 n-tiles
  int brow = (swz >> 5) * BM;   // 16 m-tiles

  const unsigned short* Abase = A + (size_t)brow * K;
  const unsigned short* Bbase = Bt + (size_t)bcol * K;

  // Staging (rule 21): LDS dest linear; SOURCE slot pre-swizzled with the
  // same involution the reader applies: slot' = slot ^ ((row>>1)&3).
  // 3 gload_lds per thread per tile (2 A + 1 B) -> vmcnt units.
  auto stage = [&](int buf, int tile) {
    int kt = tile * BK;
#pragma unroll
    for (int r = 0; r < 2; ++r) {
      int chunk = r * 256 + tid;          // 0..511 (A: 128 rows x 4 slots)
      int row = chunk >> 2;
      int sp = chunk & 3;
      int kof = (sp ^ ((row >> 1) & 3)) * 8;
      gload_lds16(Abase + (size_t)row * K + kt + kof,
                  &As[buf][(size_t)(r * 256 + wid * 64) * 8]);
    }
    {
      int row = tid >> 2;                 // B: 64 rows x 4 slots
      int sp = tid & 3;
      int kof = (sp ^ ((row >> 1) & 3)) * 8;
      gload_lds16(Bbase + (size_t)row * K + kt + kof,
                  &Bs[buf][(size_t)(wid * 64) * 8]);
    }
  };

  f32x4 acc[4][2];
#pragma unroll
  for (int i = 0; i < 4; ++i)
#pragma unroll
    for (int j = 0; j < 2; ++j) acc[i][j] = f32x4{0.f, 0.f, 0.f, 0.f};

  auto compute = [&](int buf) {
    short8 a[4], b[2];
#pragma unroll
    for (int mt = 0; mt < 4; ++mt) {
      int row = wr * 64 + mt * 16 + lr;
      int slot = lg ^ ((row >> 1) & 3);
      a[mt] = *reinterpret_cast<const short8*>(&As[buf][row * BK + slot * 8]);
    }
#pragma unroll
    for (int nt = 0; nt < 2; ++nt) {
      int row = wc * 32 + nt * 16 + lr;
      int slot = lg ^ ((row >> 1) & 3);
      b[nt] = *reinterpret_cast<const short8*>(&Bs[buf][row * BK + slot * 8]);
    }
#pragma unroll
    for (int mt = 0; mt < 4; ++mt)
#pragma unroll
      for (int nt = 0; nt < 2; ++nt)
        acc[mt][nt] = __builtin_amdgcn_mfma_f32_16x16x32_bf16(
            a[mt], b[nt], acc[mt][nt], 0, 0, 0);
  };

  // wcase: 0 -> vmcnt(6) (2 newer tiles in flight), 1 -> vmcnt(3), 2 -> 0.
  auto step = [&](int buf, int pf_tile, int wcase) {
    if (wcase == 0) waitv6();
    else if (wcase == 1) waitv3();
    else waitv0();
    __builtin_amdgcn_s_barrier();          // buffer `buf` fully written
    __builtin_amdgcn_sched_barrier(0);
    compute(buf);
    waitlgkm0();                           // my ds_reads retired
    __builtin_amdgcn_s_barrier();          // all waves done reading `buf`
    __builtin_amdgcn_sched_barrier(0);
    if (pf_tile < NT) stage(buf, pf_tile);
  };

  stage(0, 0); stage(1, 1); stage(2, 2);   // 9 loads/thread in flight
#pragma unroll 1
  for (int i = 0; i < 20; ++i) {           // tiles 0..59
    int t = 3 * i;
    step(0, t + 3, 0);
    step(1, t + 4, 0);
    step(2, t + 5, 0);
  }
  step(0, 63, 0);                          // tile 60 (prefetch 63)
  step(1, NT, 0);                          // tile 61
  step(2, NT, 1);                          // tile 62
  step(0, NT, 2);                          // tile 63

  // epilogue: C/D layout col=lane&15, row=(lane>>4)*4+reg  [m89-verified]
#pragma unroll
  for (int nt = 0; nt < 2; ++nt) {
    int col = bcol + wc * 32 + nt * 16 + lr;
    float bs = bias[col];
#pragma unroll
    for (int mt = 0; mt < 4; ++mt) {
#pragma unroll
      for (int i = 0; i < 4; ++i) {
        int row = brow + wr * 64 + mt * 16 + lg * 4 + i;
        float v = acc[mt][nt][i] + bs;
        if (EPI == 1) v = tanhf(v);
        else v = fmaxf(v, 0.0f);
        if (EPI == 2) Cf[(size_t)row * N + col] = v;
        else Cb[(size_t)row * N + col] = f2bf(v);
      }
    }
  }

  // ---- transpose tail: tdst[n*D+k] = bf16(tsrc[k*D+n]) for a later GEMM.
  // 1024 64x64 tiles over 512 blocks = 2 tiles/block. Reuses As as f32 LDS.
  if (tsrc != nullptr) {
    float* ft = reinterpret_cast<float*>(&As[0][0]);  // 64*65 f32 = 16.25KB
    __syncthreads();
#pragma unroll 1
    for (int t2 = 0; t2 < 2; ++t2) {
      int tau = bid * 2 + t2;
      int bx = (tau & 31) * 64;   // n base
      int by = (tau >> 5) * 64;   // k base
      if (t2) __syncthreads();
#pragma unroll
      for (int it = 0; it < 4; ++it) {
        int idx = it * 256 + tid;
        int r = idx >> 4, c4 = (idx & 15) * 4;
        float4 v = *reinterpret_cast<const float4*>(
            &tsrc[(size_t)(by + r) * DD + bx + c4]);
        ft[r * 65 + c4 + 0] = v.x;
        ft[r * 65 + c4 + 1] = v.y;
        ft[r * 65 + c4 + 2] = v.z;
        ft[r * 65 + c4 + 3] = v.w;
      }
      __syncthreads();
#pragma unroll
      for (int it = 0; it < 4; ++it) {
        int idx = it * 256 + tid;
        int n = idx >> 4, kq = idx & 15;
        ushort4 o;
        o.x = f2bf(ft[(kq * 4 + 0) * 65 + n]);
        o.y = f2bf(ft[(kq * 4 + 1) * 65 + n]);
        o.z = f2bf(ft[(kq * 4 + 2) * 65 + n]);
        o.w = f2bf(ft[(kq * 4 + 3) * 65 + n]);
        *reinterpret_cast<ushort4*>(&tdst[(size_t)(bx + n) * DD + by + kq * 4]) = o;
      }
    }
  }
}

// ---------------- launch ----------------

extern "C" void kernel_launch(void* const* d_in, const int* in_sizes, int n_in,
                              void* d_out, int out_size, void* d_ws,
                              size_t ws_size, hipStream_t stream) {
  const float* x     = (const float*)d_in[0];
  const float* w0    = (const float*)d_in[1];
  const float* b0    = (const float*)d_in[2];
  const float* w1    = (const float*)d_in[3];
  const float* b1    = (const float*)d_in[4];
  const float* infw1 = (const float*)d_in[5];
  const float* clsw1 = (const float*)d_in[6];
  const float* clsb1 = (const float*)d_in[7];
  const float* w2    = (const float*)d_in[8];
  const float* b2    = (const float*)d_in[9];
  const float* infw2 = (const float*)d_in[10];
  const float* clsw2 = (const float*)d_in[11];
  const float* clsb2 = (const float*)d_in[12];
  const float* w3    = (const float*)d_in[13];
  const float* b3    = (const float*)d_in[14];
  float* out = (float*)d_out;

  char* ws = (char*)d_ws;
  const size_t MB = 1ull << 20;
  const size_t DDe = (size_t)DD * DD;
  unsigned short* buf0 = (unsigned short*)ws;              // 8 MB (x_bf16 / act)
  unsigned short* buf1 = (unsigned short*)(ws + 8 * MB);   // 8 MB (act)
  unsigned short* wts  = (unsigned short*)(ws + 16 * MB);  // 6 x 8 MB
  float* padd1 = (float*)(ws + 64 * MB);
  float* padd2 = padd1 + DD;

  transpose2_kernel<<<dim3(DD / 32, DD / 32, 2), dim3(32, 8), 0, stream>>>(
      w0, w1, wts);
  cvt_bf16_kernel<<<(int)(DDe / 4 / 256), 256, 0, stream>>>(x, buf0,
                                                            (int)(DDe / 4));
  padd_kernel<<<dim3(DD / 256, 2), 256, 0, stream>>>(infw1, infw2, clsb1,
                                                     clsb2, padd1, padd2);

  dim3 gg((DD / BM) * (DD / BN));  // 512 blocks -> 2 blocks/CU
  // GEMM_i tail-transposes the weight consumed by GEMM_{i+2} (stream order
  // guarantees GEMM_i completes before GEMM_{i+1} starts).
  gemm_kernel<0><<<gg, 256, 0, stream>>>(buf0, wts + 0 * DDe, b0,    buf1,
                                         nullptr, clsw1, wts + 2 * DDe);
  gemm_kernel<0><<<gg, 256, 0, stream>>>(buf1, wts + 1 * DDe, b1,    buf0,
                                         nullptr, w2,    wts + 3 * DDe);
  gemm_kernel<1><<<gg, 256, 0, stream>>>(buf0, wts + 2 * DDe, padd1, buf1,
                                         nullptr, clsw2, wts + 4 * DDe);
  gemm_kernel<0><<<gg, 256, 0, stream>>>(buf1, wts + 3 * DDe, b2,    buf0,
                                         nullptr, w3,    wts + 5 * DDe);
  gemm_kernel<1><<<gg, 256, 0, stream>>>(buf0, wts + 4 * DDe, padd2, buf1,
                                         nullptr, nullptr, nullptr);
  gemm_kernel<2><<<gg, 256, 0, stream>>>(buf1, wts + 5 * DDe, b3,    nullptr,
                                         out, nullptr, nullptr);
}

// Round 7
// 219.007 us; speedup vs baseline: 1.6849x; 1.1302x over previous
//
#include <hip/hip_runtime.h>
#include <hip/hip_bf16.h>

// InfiniteNeuralNetwork: the scan state stays row-constant, so
//   p[j] = (1/D) * prod_{d,k} cos^2(inf_w[d,j,k])
// and each infinite layer is just tanh(x @ cls_w + cls_b + p).
// Network = 6 GEMMs [2048x2048x2048] with fused epilogues.
// R3: XOR-swizzle fixed 16-way LDS conflicts (93 -> ~41us/GEMM).
// R4: depth-3 counted-vmcnt pipeline (~35us/GEMM). Still 1 block/CU.
// R5: BN=64/BK=32, 512 blocks = 2/CU + swizzle + pipeline; weight
//     transposes hidden in GEMM tails. 247us.
// R6: LDS-repacked vectorized epilogue (16B stores, was 2B scatter) +
//     s_setprio(1) around MFMA cluster (T5: 2 blocks/CU role diversity).

#define DD 2048
#define DEPTH 9

#define BM 128
#define BN 64
#define BK 32
#define NT (DD / BK)   // 64 K-tiles

typedef __attribute__((ext_vector_type(8))) short short8;
typedef __attribute__((ext_vector_type(4))) float f32x4;

__device__ __forceinline__ unsigned short f2bf(float f) {
  unsigned u = __float_as_uint(f);
  u += 0x7FFFu + ((u >> 16) & 1u);   // round-to-nearest-even
  return (unsigned short)(u >> 16);
}

// ---------------- prep kernels ----------------

__global__ void cvt_bf16_kernel(const float* __restrict__ s,
                                unsigned short* __restrict__ d, int n4) {
  int i = blockIdx.x * 256 + threadIdx.x;
  if (i >= n4) return;
  float4 v = reinterpret_cast<const float4*>(s)[i];
  ushort4 o;
  o.x = f2bf(v.x); o.y = f2bf(v.y); o.z = f2bf(v.z); o.w = f2bf(v.w);
  reinterpret_cast<ushort4*>(d)[i] = o;
}

// dst[z][n*D + k] = bf16(src_z[k*D + n])  for w0, w1 (needed immediately)
__global__ void transpose2_kernel(const float* __restrict__ s0,
                                  const float* __restrict__ s1,
                                  unsigned short* __restrict__ wts) {
  __shared__ float tile[32][33];
  const float* src = blockIdx.z ? s1 : s0;
  unsigned short* dst = wts + (size_t)blockIdx.z * DD * DD;
  int bx = blockIdx.x * 32;  // n base
  int by = blockIdx.y * 32;  // k base
  int tx = threadIdx.x, ty = threadIdx.y;
#pragma unroll
  for (int i = ty; i < 32; i += 8)
    tile[i][tx] = src[(size_t)(by + i) * DD + bx + tx];
  __syncthreads();
#pragma unroll
  for (int i = ty; i < 32; i += 8)
    dst[(size_t)(bx + i) * DD + by + tx] = f2bf(tile[tx][i]);
}

// padd[j] = cls_b[j] + (1/D) * prod_{d,k} cos^2(inf_w[d,j,k])  (both layers)
__global__ void padd_kernel(const float* __restrict__ infw1,
                            const float* __restrict__ infw2,
                            const float* __restrict__ clsb1,
                            const float* __restrict__ clsb2,
                            float* __restrict__ padd1,
                            float* __restrict__ padd2) {
  int j = blockIdx.x * 256 + threadIdx.x;
  if (j >= DD) return;
  const float* inf_w = blockIdx.y ? infw2 : infw1;
  const float* cls_b = blockIdx.y ? clsb2 : clsb1;
  float* padd = blockIdx.y ? padd2 : padd1;
  float prod = 1.0f;
#pragma unroll
  for (int d = 0; d < DEPTH; ++d) {
    const float* row = inf_w + ((size_t)d * DD + j) * DD;
    prod *= cosf(row[0]) * cosf(row[1]) * cosf(row[2]);
  }
  padd[j] = cls_b[j] + prod * prod * (1.0f / (float)DD);
}

// ---------------- GEMM ----------------

__device__ __forceinline__ void gload_lds16(const unsigned short* g,
                                            unsigned short* l) {
  __builtin_amdgcn_global_load_lds(
      (const __attribute__((address_space(1))) void*)g,
      (__attribute__((address_space(3))) void*)l, 16, 0, 0);
}

__device__ __forceinline__ void waitv6() {
  asm volatile("s_waitcnt vmcnt(6)" ::: "memory");
}
__device__ __forceinline__ void waitv3() {
  asm volatile("s_waitcnt vmcnt(3)" ::: "memory");
}
__device__ __forceinline__ void waitv0() {
  asm volatile("s_waitcnt vmcnt(0)" ::: "memory");
}
__device__ __forceinline__ void waitlgkm0() {
  asm volatile("s_waitcnt lgkmcnt(0)" ::: "memory");
}

// EPI: 0 = relu -> bf16, 1 = tanh -> bf16, 2 = relu -> f32
// A: [M][K] bf16 row-major. Bt: [N][K] bf16 (transposed weight). bias: [N] f32.
// tsrc/tdst: optional weight transpose tail (for a LATER gemm's weight).
template <int EPI>
__global__ __launch_bounds__(256) void gemm_kernel(
    const unsigned short* __restrict__ A, const unsigned short* __restrict__ Bt,
    const float* __restrict__ bias, unsigned short* __restrict__ Cb,
    float* __restrict__ Cf, const float* __restrict__ tsrc,
    unsigned short* __restrict__ tdst) {
  const int N = DD, K = DD;
  // 36KB union: pipeline buffers (24KB A + 12KB B) / epilogue f32 tile
  // (128*68*4 = 34816B) / tail transpose tile (64*65*4 = 16.9KB).
  __shared__ __align__(16) unsigned char smem[36864];
  unsigned short* As = (unsigned short*)smem;                    // 3 x 4096 el
  unsigned short* Bs = (unsigned short*)(smem + 3 * BM * BK * 2);// 3 x 2048 el

  int tid = threadIdx.x;
  int wid = tid >> 6, lane = tid & 63;
  int wr = wid >> 1, wc = wid & 1;   // wave grid 2x2, wave tile 64x32
  int lr = lane & 15;
  int lg = lane >> 4;

  // XCD-aware bijective swizzle over 512 blocks (512 % 8 == 0).
  int bid = blockIdx.x;
  int swz = (bid & 7) * 64 + (bid >> 3);
  int bcol = (swz & 31) * BN;   // 32 n-tiles
  int brow = (swz >> 5) * BM;   // 16 m-tiles

  const unsigned short* Abase = A + (size_t)brow * K;
  const unsigned short* Bbase = Bt + (size_t)bcol * K;

  // Staging (rule 21): LDS dest linear; SOURCE slot pre-swizzled with the
  // same involution the reader applies: slot' = slot ^ ((row>>1)&3).
  // 3 gload_lds per thread per tile (2 A + 1 B) -> vmcnt units.
  auto stage = [&](int buf, int tile) {
    int kt = tile * BK;
#pragma unroll
    for (int r = 0; r < 2; ++r) {
      int chunk = r * 256 + tid;          // 0..511 (A: 128 rows x 4 slots)
      int row = chunk >> 2;
      int sp = chunk & 3;
      int kof = (sp ^ ((row >> 1) & 3)) * 8;
      gload_lds16(Abase + (size_t)row * K + kt + kof,
                  As + buf * (BM * BK) + (size_t)(r * 256 + wid * 64) * 8);
    }
    {
      int row = tid >> 2;                 // B: 64 rows x 4 slots
      int sp = tid & 3;
      int kof = (sp ^ ((row >> 1) & 3)) * 8;
      gload_lds16(Bbase + (size_t)row * K + kt + kof,
                  Bs + buf * (BN * BK) + (size_t)(wid * 64) * 8);
    }
  };

  f32x4 acc[4][2];
#pragma unroll
  for (int i = 0; i < 4; ++i)
#pragma unroll
    for (int j = 0; j < 2; ++j) acc[i][j] = f32x4{0.f, 0.f, 0.f, 0.f};

  auto compute = [&](int buf) {
    short8 a[4], b[2];
#pragma unroll
    for (int mt = 0; mt < 4; ++mt) {
      int row = wr * 64 + mt * 16 + lr;
      int slot = lg ^ ((row >> 1) & 3);
      a[mt] = *reinterpret_cast<const short8*>(
          &As[buf * (BM * BK) + row * BK + slot * 8]);
    }
#pragma unroll
    for (int nt = 0; nt < 2; ++nt) {
      int row = wc * 32 + nt * 16 + lr;
      int slot = lg ^ ((row >> 1) & 3);
      b[nt] = *reinterpret_cast<const short8*>(
          &Bs[buf * (BN * BK) + row * BK + slot * 8]);
    }
    __builtin_amdgcn_s_setprio(1);         // T5: favor MFMA-entering wave
#pragma unroll
    for (int mt = 0; mt < 4; ++mt)
#pragma unroll
      for (int nt = 0; nt < 2; ++nt)
        acc[mt][nt] = __builtin_amdgcn_mfma_f32_16x16x32_bf16(
            a[mt], b[nt], acc[mt][nt], 0, 0, 0);
    __builtin_amdgcn_s_setprio(0);
  };

  // wcase: 0 -> vmcnt(6) (2 newer tiles in flight), 1 -> vmcnt(3), 2 -> 0.
  auto step = [&](int buf, int pf_tile, int wcase) {
    if (wcase == 0) waitv6();
    else if (wcase == 1) waitv3();
    else waitv0();
    __builtin_amdgcn_s_barrier();          // buffer `buf` fully written
    __builtin_amdgcn_sched_barrier(0);
    compute(buf);
    waitlgkm0();                           // my ds_reads retired
    __builtin_amdgcn_s_barrier();          // all waves done reading `buf`
    __builtin_amdgcn_sched_barrier(0);
    if (pf_tile < NT) stage(buf, pf_tile);
  };

  stage(0, 0); stage(1, 1); stage(2, 2);   // 9 loads/thread in flight
#pragma unroll 1
  for (int i = 0; i < 20; ++i) {           // tiles 0..59
    int t = 3 * i;
    step(0, t + 3, 0);
    step(1, t + 4, 0);
    step(2, t + 5, 0);
  }
  step(0, 63, 0);                          // tile 60 (prefetch 63)
  step(1, NT, 0);                          // tile 61
  step(2, NT, 1);                          // tile 62
  step(0, NT, 2);                          // tile 63

  // ---- epilogue: LDS-repack to coalesced 16B stores.
  // C/D layout col=lane&15, row=(lane>>4)*4+reg [m89-verified].
  {
    float* et = reinterpret_cast<float*>(smem);   // [128][68] f32
#pragma unroll
    for (int nt = 0; nt < 2; ++nt) {
      int colb = wc * 32 + nt * 16 + lr;
      float bs = bias[bcol + colb];
#pragma unroll
      for (int mt = 0; mt < 4; ++mt) {
#pragma unroll
        for (int i = 0; i < 4; ++i) {
          int rowb = wr * 64 + mt * 16 + lg * 4 + i;
          float v = acc[mt][nt][i] + bs;
          v = (EPI == 1) ? tanhf(v) : fmaxf(v, 0.0f);
          et[rowb * 68 + colb] = v;
        }
      }
    }
    __syncthreads();
#pragma unroll
    for (int it = 0; it < 4; ++it) {
      int chunk = it * 256 + tid;          // 1024 chunks of 8 elements
      int rowb = chunk >> 3;
      int c8 = (chunk & 7) * 8;
      float4 v0 = *reinterpret_cast<const float4*>(&et[rowb * 68 + c8]);
      float4 v1 = *reinterpret_cast<const float4*>(&et[rowb * 68 + c8 + 4]);
      size_t g = (size_t)(brow + rowb) * N + bcol + c8;
      if (EPI == 2) {
        *reinterpret_cast<float4*>(&Cf[g]) = v0;
        *reinterpret_cast<float4*>(&Cf[g + 4]) = v1;
      } else {
        uint4 o;
        o.x = (unsigned)f2bf(v0.x) | ((unsigned)f2bf(v0.y) << 16);
        o.y = (unsigned)f2bf(v0.z) | ((unsigned)f2bf(v0.w) << 16);
        o.z = (unsigned)f2bf(v1.x) | ((unsigned)f2bf(v1.y) << 16);
        o.w = (unsigned)f2bf(v1.z) | ((unsigned)f2bf(v1.w) << 16);
        *reinterpret_cast<uint4*>(&Cb[g]) = o;
      }
    }
  }

  // ---- transpose tail: tdst[n*D+k] = bf16(tsrc[k*D+n]) for a later GEMM.
  // 1024 64x64 tiles over 512 blocks = 2 tiles/block.
  if (tsrc != nullptr) {
    float* ft = reinterpret_cast<float*>(smem);  // 64*65 f32 = 16.25KB
    __syncthreads();
#pragma unroll 1
    for (int t2 = 0; t2 < 2; ++t2) {
      int tau = bid * 2 + t2;
      int bx = (tau & 31) * 64;   // n base
      int by = (tau >> 5) * 64;   // k base
      if (t2) __syncthreads();
#pragma unroll
      for (int it = 0; it < 4; ++it) {
        int idx = it * 256 + tid;
        int r = idx >> 4, c4 = (idx & 15) * 4;
        float4 v = *reinterpret_cast<const float4*>(
            &tsrc[(size_t)(by + r) * DD + bx + c4]);
        ft[r * 65 + c4 + 0] = v.x;
        ft[r * 65 + c4 + 1] = v.y;
        ft[r * 65 + c4 + 2] = v.z;
        ft[r * 65 + c4 + 3] = v.w;
      }
      __syncthreads();
#pragma unroll
      for (int it = 0; it < 4; ++it) {
        int idx = it * 256 + tid;
        int n = idx >> 4, kq = idx & 15;
        ushort4 o;
        o.x = f2bf(ft[(kq * 4 + 0) * 65 + n]);
        o.y = f2bf(ft[(kq * 4 + 1) * 65 + n]);
        o.z = f2bf(ft[(kq * 4 + 2) * 65 + n]);
        o.w = f2bf(ft[(kq * 4 + 3) * 65 + n]);
        *reinterpret_cast<ushort4*>(&tdst[(size_t)(bx + n) * DD + by + kq * 4]) = o;
      }
    }
  }
}

// ---------------- launch ----------------

extern "C" void kernel_launch(void* const* d_in, const int* in_sizes, int n_in,
                              void* d_out, int out_size, void* d_ws,
                              size_t ws_size, hipStream_t stream) {
  const float* x     = (const float*)d_in[0];
  const float* w0    = (const float*)d_in[1];
  const float* b0    = (const float*)d_in[2];
  const float* w1    = (const float*)d_in[3];
  const float* b1    = (const float*)d_in[4];
  const float* infw1 = (const float*)d_in[5];
  const float* clsw1 = (const float*)d_in[6];
  const float* clsb1 = (const float*)d_in[7];
  const float* w2    = (const float*)d_in[8];
  const float* b2    = (const float*)d_in[9];
  const float* infw2 = (const float*)d_in[10];
  const float* clsw2 = (const float*)d_in[11];
  const float* clsb2 = (const float*)d_in[12];
  const float* w3    = (const float*)d_in[13];
  const float* b3    = (const float*)d_in[14];
  float* out = (float*)d_out;

  char* ws = (char*)d_ws;
  const size_t MB = 1ull << 20;
  const size_t DDe = (size_t)DD * DD;
  unsigned short* buf0 = (unsigned short*)ws;              // 8 MB (x_bf16 / act)
  unsigned short* buf1 = (unsigned short*)(ws + 8 * MB);   // 8 MB (act)
  unsigned short* wts  = (unsigned short*)(ws + 16 * MB);  // 6 x 8 MB
  float* padd1 = (float*)(ws + 64 * MB);
  float* padd2 = padd1 + DD;

  transpose2_kernel<<<dim3(DD / 32, DD / 32, 2), dim3(32, 8), 0, stream>>>(
      w0, w1, wts);
  cvt_bf16_kernel<<<(int)(DDe / 4 / 256), 256, 0, stream>>>(x, buf0,
                                                            (int)(DDe / 4));
  padd_kernel<<<dim3(DD / 256, 2), 256, 0, stream>>>(infw1, infw2, clsb1,
                                                     clsb2, padd1, padd2);

  dim3 gg((DD / BM) * (DD / BN));  // 512 blocks -> 2 blocks/CU
  // GEMM_i tail-transposes the weight consumed by GEMM_{i+2} (stream order
  // guarantees GEMM_i completes before GEMM_{i+1} starts).
  gemm_kernel<0><<<gg, 256, 0, stream>>>(buf0, wts + 0 * DDe, b0,    buf1,
                                         nullptr, clsw1, wts + 2 * DDe);
  gemm_kernel<0><<<gg, 256, 0, stream>>>(buf1, wts + 1 * DDe, b1,    buf0,
                                         nullptr, w2,    wts + 3 * DDe);
  gemm_kernel<1><<<gg, 256, 0, stream>>>(buf0, wts + 2 * DDe, padd1, buf1,
                                         nullptr, clsw2, wts + 4 * DDe);
  gemm_kernel<0><<<gg, 256, 0, stream>>>(buf1, wts + 3 * DDe, b2,    buf0,
                                         nullptr, w3,    wts + 5 * DDe);
  gemm_kernel<1><<<gg, 256, 0, stream>>>(buf0, wts + 4 * DDe, padd2, buf1,
                                         nullptr, nullptr, nullptr);
  gemm_kernel<2><<<gg, 256, 0, stream>>>(buf1, wts + 5 * DDe, b3,    nullptr,
                                         out, nullptr, nullptr);
}